// Round 8
// baseline (121.879 us; speedup 1.0000x reference)
//
#include <hip/hip_runtime.h>
#include <hip/hip_bf16.h>
#include <hip/hip_fp8.h>

// Problem shape (fixed by setup_inputs)
#define SEQ   16384
#define DIN_  2048
#define DOUT_ 1024
#define NE_   8
#define TPE   (SEQ / NE_)   // 2048 tokens per expert
#define NT    (DIN_ / 64)   // 32 K-tiles of 64

typedef __bf16 bf16x8 __attribute__((ext_vector_type(8)));
typedef __bf16 bf16x4 __attribute__((ext_vector_type(4)));
typedef float  f32x4  __attribute__((ext_vector_type(4)));

// async global->LDS, 16B per lane. LDS dest must be wave-linear (base + lane*16).
#define GLD(gp, lp) __builtin_amdgcn_global_load_lds( \
    (const __attribute__((address_space(1))) unsigned int*)(gp), \
    (__attribute__((address_space(3))) unsigned int*)(lp), 16, 0, 0)

// Reference fp8_round with the tile-wide divide hoisted: r = v*(1/scale)
__device__ __forceinline__ float fp8_round_dq_m(float v, float sinv, float s) {
    float r = v * sinv;
    r = fminf(fmaxf(r, -448.0f), 448.0f);
    __hip_fp8_e4m3 q(r);   // OCP e4m3fn, RNE, saturated
    return (float)q * s;
}

// ---------------- activation quant-dequant: 1x128 tiles, 4 rows per block ----------------
__global__ __launch_bounds__(256) void quant_x_kernel(const float* __restrict__ X,
                                                      __bf16* __restrict__ Xq) {
    const int t    = threadIdx.x;
    const int lane = t & 63;
    const int wave = t >> 6;
    const int tile = wave * 4 + (lane >> 4);   // 0..15
    const int sub  = lane & 15;
    const size_t off = (size_t)tile * 128 + sub * 8;

    const int row0 = blockIdx.x * 4;
    float4 v0[4], v1[4];
    float mx[4];
    #pragma unroll
    for (int r = 0; r < 4; ++r) {
        const float* p = X + (size_t)(row0 + r) * DIN_ + off;
        v0[r] = *(const float4*)p;
        v1[r] = *(const float4*)(p + 4);
        mx[r] = fmaxf(fmaxf(fmaxf(fabsf(v0[r].x), fabsf(v0[r].y)),
                            fmaxf(fabsf(v0[r].z), fabsf(v0[r].w))),
                      fmaxf(fmaxf(fabsf(v1[r].x), fabsf(v1[r].y)),
                            fmaxf(fabsf(v1[r].z), fabsf(v1[r].w))));
    }
    #pragma unroll
    for (int o = 1; o < 16; o <<= 1) {
        #pragma unroll
        for (int r = 0; r < 4; ++r)
            mx[r] = fmaxf(mx[r], __shfl_xor(mx[r], o, 64));
    }
    #pragma unroll
    for (int r = 0; r < 4; ++r) {
        const float s    = fmaxf(mx[r], 1e-12f) / 448.0f;
        const float sinv = 1.0f / s;
        bf16x8 o;
        o[0] = (__bf16)fp8_round_dq_m(v0[r].x, sinv, s);
        o[1] = (__bf16)fp8_round_dq_m(v0[r].y, sinv, s);
        o[2] = (__bf16)fp8_round_dq_m(v0[r].z, sinv, s);
        o[3] = (__bf16)fp8_round_dq_m(v0[r].w, sinv, s);
        o[4] = (__bf16)fp8_round_dq_m(v1[r].x, sinv, s);
        o[5] = (__bf16)fp8_round_dq_m(v1[r].y, sinv, s);
        o[6] = (__bf16)fp8_round_dq_m(v1[r].z, sinv, s);
        o[7] = (__bf16)fp8_round_dq_m(v1[r].w, sinv, s);
        *(bf16x8*)(Xq + (size_t)(row0 + r) * DIN_ + off) = o;
    }
}

// ---------------- weight quant-dequant: 128x128 blocks ----------------
__global__ __launch_bounds__(256) void quant_w_kernel(const float* __restrict__ W,
                                                      __bf16* __restrict__ Wq) {
    const int rb = blockIdx.x >> 4;
    const int cb = blockIdx.x & 15;
    const int t  = threadIdx.x;

    const float* base = W + (size_t)(rb * 128) * DIN_ + cb * 128;
    const int r0 = t >> 5;
    const int c0 = (t & 31) * 4;

    float4 v[16];
    float m = 0.0f;
    #pragma unroll
    for (int i = 0; i < 16; ++i) {
        v[i] = *(const float4*)(base + (size_t)(i * 8 + r0) * DIN_ + c0);
        m = fmaxf(m, fmaxf(fmaxf(fabsf(v[i].x), fabsf(v[i].y)),
                           fmaxf(fabsf(v[i].z), fabsf(v[i].w))));
    }
    #pragma unroll
    for (int off = 1; off < 64; off <<= 1)
        m = fmaxf(m, __shfl_xor(m, off, 64));
    __shared__ float smx[4];
    if ((t & 63) == 0) smx[t >> 6] = m;
    __syncthreads();
    const float amax = fmaxf(fmaxf(smx[0], smx[1]), fmaxf(smx[2], smx[3]));
    const float s    = fmaxf(amax, 1e-12f) / 448.0f;
    const float sinv = 1.0f / s;

    __bf16* obase = Wq + (size_t)(rb * 128) * DIN_ + cb * 128;
    #pragma unroll
    for (int i = 0; i < 16; ++i) {
        bf16x4 o;
        o[0] = (__bf16)fp8_round_dq_m(v[i].x, sinv, s);
        o[1] = (__bf16)fp8_round_dq_m(v[i].y, sinv, s);
        o[2] = (__bf16)fp8_round_dq_m(v[i].z, sinv, s);
        o[3] = (__bf16)fp8_round_dq_m(v[i].w, sinv, s);
        *(bf16x4*)(obase + (size_t)(i * 8 + r0) * DIN_ + c0) = o;
    }
}

// ---------------- grouped GEMM: 256x256, BK=64 ------------------------------------------
// R7 pre-read schedule + R5 bank-optimal full-width layout.
// LDS 128 KiB = 4 full-tile regions [256 rows][128 B]:
//   A(buf) @ buf*32768 ; B(buf) @ 65536 + buf*32768.
// Swizzle: 16B-slot(3b) ^= row&7  (byte p ^= ((p>>7)&7)<<4): a wave b128 read = 16 rows
// x 4 kc-slots -> 8 slots x 8 lanes = 8-cycle minimum service (bank-optimal).
// Staging: full 32KB tile, 4 GLD16/thread, dest p = t*16 (lane-linear), source
// inverse-swizzled -> 8 lanes read one full 128B line (perfectly coalesced).
// Pre-reads one phase ahead (drain under MFMA):
//   ph4(kt-1): aA=A-kh0 m0-3 + b0=B-kh0 [8] | ph1: aB=A-kh0 m4-7 [4]
//   ph2: aA=A-kh1 m0-3 + b1=B-kh1 [8]       | ph3: aB=A-kh1 m4-7 [4]
// lgkm gates: ph1(4) ph2(8) ph3(4) ph4(8|0). Invariant: 8 outstanding at phase entry.
// Stages AFTER the phase's lgkm drain (no write-arrival race):
//   ph3: B(kt+2) [B(kt) reads drained by ph3 lgkm(4)]
//   ph4: A(kt+2) [A(kt) reads drained by ph4 lgkm(8)]
// vmcnt (units of 4 GLD), once per K-tile at end-ph3:
//   steady: outstanding {A(kt+1),B(kt+1),B(kt+2)} -> vmcnt(4) ensures tile kt+1 landed
//   kt>=NT-2: vmcnt(0).
__global__ __launch_bounds__(512, 2) void gemm_kernel(const __bf16* __restrict__ X,
                                                      const __bf16* __restrict__ W,
                                                      float* __restrict__ out) {
    __shared__ __align__(16) unsigned char lds[131072];

    // T1: bijective XCD swizzle; 256 blocks = 8 XCDs x 32 (one expert per XCD)
    const int bid  = blockIdx.x;
    const int wgid = (bid & 7) * 32 + (bid >> 3);
    const int e    = wgid >> 5;
    const int tile = wgid & 31;
    const int brow = tile >> 2;   // 0..7
    const int bcol = tile & 3;    // 0..3

    const int t     = threadIdx.x;
    const int lane  = t & 63;
    const int wave  = t >> 6;
    const int wm    = wave >> 2;  // 0..1
    const int wn    = wave & 3;   // 0..3
    const int flane = lane & 15;

    const __bf16* Xt = X + (size_t)(e * TPE + brow * 256) * DIN_;
    const __bf16* Wt = W + (size_t)(e * DOUT_ + bcol * 256) * DIN_;

    // stage one full tile (32 KiB): 4 GLD16/thread, linear dest, inverse-swizzled source
    auto stage = [&](int j, bool isA) {
        if (j >= NT) return;
        const unsigned base = (isA ? 0u : 65536u) + (unsigned)(j & 1) * 32768u;
        const __bf16* src = isA ? Xt : Wt;
        #pragma unroll
        for (int i = 0; i < 4; ++i) {
            const unsigned p = (unsigned)i * 8192u + (unsigned)t * 16u;
            const unsigned q = p ^ (((p >> 7) & 7u) << 4);   // involution
            GLD(src + (size_t)(q >> 7) * DIN_ + j * 64 + ((q & 127u) >> 1),
                &lds[base + p]);
        }
    };

    auto ldf = [&](unsigned base, int row, int kh) -> bf16x8 {
        unsigned p = (unsigned)row * 128u + (unsigned)kh * 64u + (unsigned)(lane >> 4) * 16u;
        p ^= ((p >> 7) & 7u) << 4;
        return *(const bf16x8*)&lds[base + p];
    };

    bf16x8 aA[4], aB[4], b0[4], b1[4];
    f32x4 acc[8][4] = {};

    #define ABASE(buf) ((unsigned)(buf) * 32768u)
    #define BBASE(buf) (65536u + (unsigned)(buf) * 32768u)
    #define PRE_A(dst, buf, kh, m0) \
        { _Pragma("unroll") for (int m_ = 0; m_ < 4; ++m_) \
            dst[m_] = ldf(ABASE(buf), wm * 128 + ((m0) + m_) * 16 + flane, kh); }
    #define PRE_B(dst, buf, kh) \
        { _Pragma("unroll") for (int n_ = 0; n_ < 4; ++n_) \
            dst[n_] = ldf(BBASE(buf), wn * 64 + n_ * 16 + flane, kh); }
    #define MFMA4x4(alo, aset, bset) \
        { _Pragma("unroll") for (int m_ = 0; m_ < 4; ++m_) \
            _Pragma("unroll") for (int n_ = 0; n_ < 4; ++n_) \
                acc[(alo) + m_][n_] = __builtin_amdgcn_mfma_f32_16x16x32_bf16( \
                    aset[m_], bset[n_], acc[(alo) + m_][n_], 0, 0, 0); }

    // prologue: tiles 0,1 (16 GLD); wait tile0 (8 newest = tile1 remain)
    stage(0, false); stage(0, true); stage(1, false); stage(1, true);
    asm volatile("s_waitcnt vmcnt(8)" ::: "memory");
    __builtin_amdgcn_s_barrier();
    PRE_A(aA, 0, 0, 0);
    PRE_B(b0, 0, 0);

    for (int kt = 0; kt < NT; ++kt) {
        const int buf = kt & 1;

        // ---- phase 1: kh0 m0-3 (aA, b0) ----
        PRE_A(aB, buf, 0, 4);                 // for ph2
        asm volatile("s_waitcnt lgkmcnt(4)" ::: "memory");   // drain aA,b0
        __builtin_amdgcn_sched_barrier(0);
        __builtin_amdgcn_s_setprio(1);
        MFMA4x4(0, aA, b0);
        __builtin_amdgcn_s_setprio(0);
        __builtin_amdgcn_s_barrier();

        // ---- phase 2: kh0 m4-7 (aB, b0) ----
        PRE_A(aA, buf, 1, 0);                 // for ph3
        PRE_B(b1, buf, 1);
        asm volatile("s_waitcnt lgkmcnt(8)" ::: "memory");   // drain aB
        __builtin_amdgcn_sched_barrier(0);
        __builtin_amdgcn_s_setprio(1);
        MFMA4x4(4, aB, b0);
        __builtin_amdgcn_s_setprio(0);
        __builtin_amdgcn_s_barrier();

        // ---- phase 3: kh1 m0-3 (aA, b1) ----
        PRE_A(aB, buf, 1, 4);                 // for ph4
        asm volatile("s_waitcnt lgkmcnt(4)" ::: "memory");   // drain aA,b1 (B(kt) done)
        __builtin_amdgcn_sched_barrier(0);
        stage(kt + 2, false);                 // B(kt+2) -> safe, B(kt) reads drained
        __builtin_amdgcn_s_setprio(1);
        MFMA4x4(0, aA, b1);
        __builtin_amdgcn_s_setprio(0);
        if (kt < NT - 2) asm volatile("s_waitcnt vmcnt(4)" ::: "memory");
        else             asm volatile("s_waitcnt vmcnt(0)" ::: "memory");
        __builtin_amdgcn_s_barrier();

        // ---- phase 4: kh1 m4-7 (aB, b1) ----
        if (kt < NT - 1) {
            PRE_A(aA, buf ^ 1, 0, 0);         // next tile kh0 m0-3
            PRE_B(b0, buf ^ 1, 0);
        }
        if (kt < NT - 1) asm volatile("s_waitcnt lgkmcnt(8)" ::: "memory");  // drain aB
        else             asm volatile("s_waitcnt lgkmcnt(0)" ::: "memory");
        __builtin_amdgcn_sched_barrier(0);
        stage(kt + 2, true);                  // A(kt+2) -> safe, A(kt) reads drained
        __builtin_amdgcn_s_setprio(1);
        MFMA4x4(4, aB, b1);
        __builtin_amdgcn_s_setprio(0);
        __builtin_amdgcn_s_barrier();
    }

    // epilogue: C/D mapping col = lane&15, row = (lane>>4)*4 + j
    const int orow0 = e * TPE + brow * 256 + wm * 128;
    const int ocol0 = bcol * 256 + wn * 64;
    const int rl = (lane >> 4) * 4;
    const int cl = lane & 15;
    #pragma unroll
    for (int m = 0; m < 8; ++m)
        #pragma unroll
        for (int n = 0; n < 4; ++n)
            #pragma unroll
            for (int j = 0; j < 4; ++j) {
                const int r = orow0 + m * 16 + rl + j;
                const int c = ocol0 + n * 16 + cl;
                out[(size_t)r * DOUT_ + c] = acc[m][n][j];
            }
}

extern "C" void kernel_launch(void* const* d_in, const int* in_sizes, int n_in,
                              void* d_out, int out_size, void* d_ws, size_t ws_size,
                              hipStream_t stream) {
    const float* x = (const float*)d_in[0];
    // d_in[1] = tokens_per_expert: reference assumes equal split, unused.
    const float* w = (const float*)d_in[2];
    float* out = (float*)d_out;

    __bf16* xq = (__bf16*)d_ws;
    __bf16* wq = (__bf16*)((char*)d_ws + (size_t)SEQ * DIN_ * sizeof(__bf16));

    quant_x_kernel<<<SEQ / 4, 256, 0, stream>>>(x, xq);
    quant_w_kernel<<<(NE_ * DOUT_ / 128) * (DIN_ / 128), 256, 0, stream>>>(w, wq);
    gemm_kernel<<<NE_ * (TPE / 256) * (DOUT_ / 256), 512, 0, stream>>>(xq, wq, out);
}